// Round 1
// baseline (7640.058 us; speedup 1.0000x reference)
//
#include <hip/hip_runtime.h>
#include <stdint.h>
#include <math.h>

#define NCLS 80
#define CINCH 256
#define KTOT 2304

static constexpr int LH[5]   = {100,50,25,13,7};
static constexpr int LW[5]   = {152,76,38,19,10};
static constexpr int LHW[5]  = {15200,3800,950,247,70};
static constexpr int LCUM[5] = {0,15200,19000,19950,20197};
static constexpr int TOTHW   = 20267;
static constexpr int LSTR[5] = {8,16,32,64,128};
static constexpr int CPX128[6] = {0,238,298,313,317,319};   // 128-px conv blocks per level (N=2*HW)
static constexpr int CPX64[6]  = {0,475,594,624,632,635};   // 64-px head blocks per level
#define NPXB128 319
#define NPXB64  635

// ---------------- helpers ----------------
__device__ __forceinline__ void lds_hist_add(uint32_t* h, uint32_t bucket) {
  unsigned long long act = __ballot(1);
  int lane = (int)(threadIdx.x & 63u);
  int leader = __ffsll(act) - 1;
  uint32_t lb = (uint32_t)__shfl((int)bucket, leader, 64);
  unsigned long long same = __ballot(bucket == lb);
  if (same == act) {
    if (lane == leader) atomicAdd(&h[bucket], (uint32_t)__popcll(act));
  } else {
    atomicAdd(&h[bucket], 1u);
  }
}

__device__ __forceinline__ uint32_t wave_append_pos(uint32_t* ctr) {
  unsigned long long act = __ballot(1);
  int lane = (int)(threadIdx.x & 63u);
  int leader = __ffsll(act) - 1;
  uint32_t cnt  = (uint32_t)__popcll(act);
  uint32_t rank = (uint32_t)__popcll(act & ((1ull << lane) - 1ull));
  uint32_t base = 0;
  if (lane == leader) base = atomicAdd(ctr, cnt);
  base = (uint32_t)__shfl((int)base, leader, 64);
  return base + rank;
}

// ---------------- stage features into act buffer ----------------
__global__ void k_stage(const float* __restrict__ p0, const float* __restrict__ p1,
                        const float* __restrict__ p2, const float* __restrict__ p3,
                        const float* __restrict__ p4, float* __restrict__ dst) {
  const size_t CB1 = (size_t)2*CINCH*LCUM[1];
  const size_t CB2 = (size_t)2*CINCH*LCUM[2];
  const size_t CB3 = (size_t)2*CINCH*LCUM[3];
  const size_t CB4 = (size_t)2*CINCH*LCUM[4];
  const size_t tot = (size_t)2*CINCH*TOTHW;
  for (size_t i = (size_t)blockIdx.x*blockDim.x + threadIdx.x; i < tot;
       i += (size_t)gridDim.x*blockDim.x) {
    float v;
    if      (i < CB1) v = p0[i];
    else if (i < CB2) v = p1[i - CB1];
    else if (i < CB3) v = p2[i - CB2];
    else if (i < CB4) v = p3[i - CB3];
    else              v = p4[i - CB4];
    dst[i] = v;
  }
}

// ---------------- main conv (implicit GEMM, fp32) ----------------
// MODE 0: tower conv 256->256, bias+ReLU, write act (NCHW per level)
// MODE 1: logits conv 256->80, sigmoid * ctr_prob, threshold, write scores [l][b][cls][hw]
template<int MODE>
__global__ __launch_bounds__(256)
void conv_k(const float* __restrict__ in, const float* __restrict__ wgt,
            const float* __restrict__ bias, float* __restrict__ out,
            const float* __restrict__ ctrp) {
  __shared__ float sA[2][1024];
  __shared__ float sB[2][1024];
  const int tid = threadIdx.x;
  int bx = blockIdx.x;
  int l = 0;
#pragma unroll
  for (int i = 1; i < 5; i++) if (bx >= CPX128[i]) l = i;
  const int pxb = bx - CPX128[l];
  const int H = LH[l], W = LW[l], HW = LHW[l];
  const int N = 2*HW;
  const int px0 = pxb*128;
  const int oc0 = blockIdx.y*128;
  const int Cout = (MODE == 0) ? CINCH : NCLS;
  const size_t lvl = (size_t)(2*CINCH)*LCUM[l];
  const float* inL = in + lvl;

  const int w_oc = tid >> 1;
  const int w_k4 = (tid & 1)*4;
  const int b_k  = tid >> 5;
  const int b_px = (tid & 31)*4;

  int lb[4], lhh[4], lww[4]; int lval[4];
#pragma unroll
  for (int i = 0; i < 4; i++) {
    int px = px0 + b_px + i;
    lval[i] = (px < N);
    int pxc = lval[i] ? px : 0;
    int bb = pxc / HW; int hw = pxc - bb*HW;
    int hh = hw / W;
    lb[i] = bb; lhh[i] = hh; lww[i] = hw - hh*W;
  }
  const bool wv = (oc0 + w_oc) < Cout;
  const float* wrow = wgt + (size_t)(oc0 + w_oc)*KTOT + w_k4;

  const int ty = tid >> 4, tx = tid & 15;

  float acc[8][8];
#pragma unroll
  for (int r = 0; r < 8; r++)
#pragma unroll
    for (int c = 0; c < 8; c++) acc[r][c] = 0.f;

  float4 wr; float br[4];
  auto load = [&](int k0) {
    wr = wv ? *reinterpret_cast<const float4*>(wrow + k0) : make_float4(0.f,0.f,0.f,0.f);
    int k = k0 + b_k;
    int c = k/9; int r = k - c*9;
    int r3 = r/3;
    int dh = r3 - 1, dw = (r - r3*3) - 1;
    const float* cb = inL + (size_t)c*HW;
#pragma unroll
    for (int i = 0; i < 4; i++) {
      int ih = lhh[i] + dh, iw = lww[i] + dw;
      bool ok = lval[i] && ((unsigned)ih < (unsigned)H) && ((unsigned)iw < (unsigned)W);
      br[i] = ok ? cb[(size_t)lb[i]*CINCH*HW + ih*W + iw] : 0.f;
    }
  };
  auto stash = [&](int buf) {
    sA[buf][(w_k4+0)*128 + w_oc] = wr.x;
    sA[buf][(w_k4+1)*128 + w_oc] = wr.y;
    sA[buf][(w_k4+2)*128 + w_oc] = wr.z;
    sA[buf][(w_k4+3)*128 + w_oc] = wr.w;
    *reinterpret_cast<float4*>(&sB[buf][b_k*128 + b_px]) = make_float4(br[0],br[1],br[2],br[3]);
  };
  auto compute = [&](int buf) {
#pragma unroll
    for (int kk = 0; kk < 8; kk++) {
      const float4 a0 = *reinterpret_cast<const float4*>(&sA[buf][kk*128 + ty*4]);
      const float4 a1 = *reinterpret_cast<const float4*>(&sA[buf][kk*128 + 64 + ty*4]);
      const float4 b0 = *reinterpret_cast<const float4*>(&sB[buf][kk*128 + tx*4]);
      const float4 b1 = *reinterpret_cast<const float4*>(&sB[buf][kk*128 + 64 + tx*4]);
      const float av[8] = {a0.x,a0.y,a0.z,a0.w,a1.x,a1.y,a1.z,a1.w};
      const float bw[8] = {b0.x,b0.y,b0.z,b0.w,b1.x,b1.y,b1.z,b1.w};
#pragma unroll
      for (int r = 0; r < 8; r++)
#pragma unroll
        for (int c = 0; c < 8; c++) acc[r][c] = fmaf(av[r], bw[c], acc[r][c]);
    }
  };

  load(0); stash(0);
  __syncthreads();
  for (int k0 = 0; k0 < KTOT; k0 += 8) {
    const int cur = (k0 >> 3) & 1;
    const bool more = (k0 + 8) < KTOT;
    if (more) load(k0 + 8);
    compute(cur);
    if (more) stash(cur ^ 1);
    __syncthreads();
  }

#pragma unroll
  for (int ch = 0; ch < 2; ch++)
#pragma unroll
  for (int ci = 0; ci < 4; ci++) {
    int px = px0 + ch*64 + tx*4 + ci;
    if (px >= N) continue;
    int bb = px / HW; int hw = px - bb*HW;
    if (MODE == 0) {
      float* ob = out + lvl + (size_t)bb*CINCH*HW + hw;
#pragma unroll
      for (int rh = 0; rh < 2; rh++)
#pragma unroll
      for (int ri = 0; ri < 4; ri++) {
        int oc = oc0 + rh*64 + ty*4 + ri;
        float v = acc[rh*4+ri][ch*4+ci] + bias[oc];
        ob[(size_t)oc*HW] = fmaxf(v, 0.f);
      }
    } else {
      float cp = ctrp[2*LCUM[l] + bb*HW + hw];
      float* ob = out + (size_t)NCLS*(2*LCUM[l] + bb*HW) + hw;
#pragma unroll
      for (int rh = 0; rh < 2; rh++)
#pragma unroll
      for (int ri = 0; ri < 4; ri++) {
        int oc = oc0 + rh*64 + ty*4 + ri;
        if (oc < NCLS) {
          float lg = acc[rh*4+ri][ch*4+ci] + bias[oc];
          float pc = 1.0f/(1.0f + expf(-lg));
          float s = pc * cp;
          s = (s > 0.05f) ? s : 0.f;
          ob[(size_t)oc*HW] = s;
        }
      }
    }
  }
}

// ---------------- ctr + reg head (256 -> 5) ----------------
__global__ __launch_bounds__(256)
void k_head(const float* __restrict__ act, const float* __restrict__ ctw,
            const float* __restrict__ ctb, const float* __restrict__ pdw,
            const float* __restrict__ pdb, const float* __restrict__ scl,
            float* __restrict__ ctrp, float* __restrict__ regb) {
  int bx = blockIdx.x; int l = 0;
#pragma unroll
  for (int i = 1; i < 5; i++) if (bx >= CPX64[i]) l = i;
  const int lblk = bx - CPX64[l];
  const int H = LH[l], W = LW[l], HW = LHW[l]; const int N = 2*HW;
  const int p = threadIdx.x & 63;
  const int q = threadIdx.x >> 6;
  const int px = lblk*64 + p;
  float a0 = 0.f, a1 = 0.f, a2 = 0.f, a3 = 0.f, a4 = 0.f;
  int bb = 0, hw = 0, hh = 0, ww = 0;
  const bool ok = (px < N);
  if (ok) {
    bb = px / HW; hw = px - bb*HW; hh = hw / W; ww = hw - hh*W;
    const float* ab = act + (size_t)(2*CINCH)*LCUM[l] + (size_t)bb*CINCH*HW;
    for (int c = q*64; c < q*64 + 64; ++c) {
      const float* xb = ab + (size_t)c*HW;
      const int k0 = c*9;
#pragma unroll
      for (int r = 0; r < 9; r++) {
        int dh = r/3 - 1, dw = r%3 - 1;
        int ih = hh + dh, iw = ww + dw;
        float xv = (((unsigned)ih < (unsigned)H) && ((unsigned)iw < (unsigned)W)) ? xb[ih*W + iw] : 0.f;
        int k = k0 + r;
        a0 = fmaf(ctw[k],          xv, a0);
        a1 = fmaf(pdw[k],          xv, a1);
        a2 = fmaf(pdw[KTOT + k],   xv, a2);
        a3 = fmaf(pdw[2*KTOT + k], xv, a3);
        a4 = fmaf(pdw[3*KTOT + k], xv, a4);
      }
    }
  }
  __shared__ float red[4][64][5];
  red[q][p][0] = a0; red[q][p][1] = a1; red[q][p][2] = a2; red[q][p][3] = a3; red[q][p][4] = a4;
  __syncthreads();
  if (q == 0 && ok) {
    float s0 = red[0][p][0] + red[1][p][0] + red[2][p][0] + red[3][p][0];
    float s1 = red[0][p][1] + red[1][p][1] + red[2][p][1] + red[3][p][1];
    float s2 = red[0][p][2] + red[1][p][2] + red[2][p][2] + red[3][p][2];
    float s3 = red[0][p][3] + red[1][p][3] + red[2][p][3] + red[3][p][3];
    float s4 = red[0][p][4] + red[1][p][4] + red[2][p][4] + red[3][p][4];
    const int gi = 2*LCUM[l] + bb*HW + hw;
    ctrp[gi] = 1.0f/(1.0f + expf(-(s0 + ctb[0])));
    const float sc = scl[l];
    float* rg = regb + (size_t)gi*4;
    rg[0] = fmaxf((s1 + pdb[0])*sc, 0.f);
    rg[1] = fmaxf((s2 + pdb[1])*sc, 0.f);
    rg[2] = fmaxf((s3 + pdb[2])*sc, 0.f);
    rg[3] = fmaxf((s4 + pdb[3])*sc, 0.f);
  }
}

// ---------------- top-k pipeline ----------------
__global__ void k_init(uint32_t* __restrict__ hist, uint32_t* __restrict__ ctrA,
                       uint32_t* __restrict__ ctrB) {
  int i = blockIdx.x*blockDim.x + threadIdx.x;
  if (i < 40960) hist[i] = 0;
  if (i < 10) { ctrA[i] = 0; ctrB[i] = 0; }
}

__global__ __launch_bounds__(256)
void k_hist(const float* __restrict__ scores, uint32_t* __restrict__ hist) {
  const int sid = blockIdx.y; const int l = sid >> 1, b = sid & 1;
  const int HW = LHW[l]; const int size = NCLS*HW;
  const float* sb = scores + (size_t)NCLS*(2*LCUM[l] + b*HW);
  __shared__ uint32_t h[4096];
  for (int i = threadIdx.x; i < 4096; i += 256) h[i] = 0;
  __syncthreads();
  const int base = blockIdx.x*4096;
  if (base < size) {
    for (int j = 0; j < 16; j++) {
      int i = base + threadIdx.x + j*256;
      if (i < size) {
        uint32_t bkt = __float_as_uint(sb[i]) >> 20;
        lds_hist_add(h, bkt);
      }
    }
  }
  __syncthreads();
  uint32_t* gh = hist + (size_t)sid*4096;
  for (int i = threadIdx.x; i < 4096; i += 256) { uint32_t v = h[i]; if (v) atomicAdd(&gh[i], v); }
}

__global__ __launch_bounds__(256)
void k_select(const uint32_t* __restrict__ hist, int* __restrict__ meta) {
  const int sid = blockIdx.x;
  const uint32_t* gh = hist + (size_t)sid*4096;
  __shared__ uint32_t ps[256];
  uint32_t sum = 0;
  for (int i = 0; i < 16; i++) sum += gh[threadIdx.x*16 + i];
  ps[threadIdx.x] = sum;
  __syncthreads();
  if (threadIdx.x == 0) {
    uint32_t c = 0; int T = 0, m = 1000;
    for (int ch = 255; ch >= 0; --ch) {
      if (c + ps[ch] >= 1000u) {
        for (int t = ch*16 + 15; t >= ch*16; --t) {
          uint32_t hv = gh[t];
          if (c + hv >= 1000u) { T = t; m = (int)(1000u - c); break; }
          c += hv;
        }
        break;
      }
      c += ps[ch];
    }
    meta[sid*4 + 0] = T;
    meta[sid*4 + 1] = (int)c;
    meta[sid*4 + 2] = m;
    meta[sid*4 + 3] = (int)gh[T];
  }
}

__global__ __launch_bounds__(256)
void k_collect(const float* __restrict__ scores, const int* __restrict__ meta,
               unsigned long long* __restrict__ listA, unsigned long long* __restrict__ listB,
               uint32_t* __restrict__ ctrA, uint32_t* __restrict__ ctrB) {
  const int sid = blockIdx.y; const int l = sid >> 1, b = sid & 1;
  const int HW = LHW[l]; const int size = NCLS*HW;
  const size_t sbase = (size_t)NCLS*(2*LCUM[l] + b*HW);
  const float* sb = scores + sbase;
  unsigned long long* lB = listB + sbase;
  unsigned long long* lA = listA + (size_t)sid*1024;
  const uint32_t T = (uint32_t)meta[sid*4];
  const int base = blockIdx.x*4096;
  if (base >= size) return;
  for (int j = 0; j < 16; j++) {
    int i = base + threadIdx.x + j*256;
    if (i >= size) continue;
    float sv = sb[i];
    uint32_t bits = __float_as_uint(sv);
    uint32_t bkt = bits >> 20;
    if (bkt < T) continue;
    int cls = i / HW; int hw = i - cls*HW;
    uint32_t idx = (uint32_t)(hw*NCLS + cls);
    unsigned long long key = ((unsigned long long)bits << 32) | (unsigned long long)(0xFFFFFFFFu - idx);
    if (bkt > T) {
      uint32_t pos = wave_append_pos(&ctrA[sid]);
      if (pos < 1024u) lA[pos] = key;
    } else {
      uint32_t pos = wave_append_pos(&ctrB[sid]);
      lB[pos] = key;
    }
  }
}

__global__ __launch_bounds__(1024)
void k_refine(const int* __restrict__ meta, const unsigned long long* __restrict__ listB,
              unsigned long long* __restrict__ listA, uint32_t* __restrict__ ctrA) {
  const int sid = blockIdx.x; const int l = sid >> 1, b = sid & 1;
  const int HW = LHW[l];
  const size_t sbase = (size_t)NCLS*(2*LCUM[l] + b*HW);
  const unsigned long long* lB = listB + sbase;
  const int nB = meta[sid*4 + 3];
  int m = meta[sid*4 + 2];
  __shared__ uint32_t h[256];
  __shared__ unsigned long long sPre;
  __shared__ int sM;
  unsigned long long prefix = 0, mask = 0;
  for (int p = 7; p >= 0; --p) {
    for (int i = threadIdx.x; i < 256; i += 1024) h[i] = 0;
    __syncthreads();
    for (int i = threadIdx.x; i < nB; i += 1024) {
      unsigned long long k = lB[i];
      if ((k & mask) == prefix) {
        uint32_t bkt = (uint32_t)((k >> (p*8)) & 255ull);
        lds_hist_add(h, bkt);
      }
    }
    __syncthreads();
    if (threadIdx.x == 0) {
      uint32_t c = 0; int sel = 0; int mnew = m;
      for (int t = 255; t >= 0; --t) {
        if (c + h[t] >= (uint32_t)m) { sel = t; mnew = m - (int)c; break; }
        c += h[t];
      }
      sPre = prefix | ((unsigned long long)sel << (p*8));
      sM = mnew;
    }
    __syncthreads();
    prefix = sPre; m = sM;
    mask |= (0xFFull << (p*8));
    __syncthreads();
  }
  for (int i = threadIdx.x; i < nB; i += 1024) {
    unsigned long long k = lB[i];
    if (k >= prefix) {
      uint32_t pos = wave_append_pos(&ctrA[sid]);
      if (pos < 1024u) listA[(size_t)sid*1024 + pos] = k;
    }
  }
}

__global__ __launch_bounds__(256)
void k_sortdec(const unsigned long long* __restrict__ listA, const uint32_t* __restrict__ ctrA,
               const float* __restrict__ regb, float* __restrict__ cbox,
               float* __restrict__ cscr, float* __restrict__ ccls) {
  const int sid = blockIdx.x; const int l = sid >> 1, b = sid & 1;
  const int HW = LHW[l], W = LW[l];
  __shared__ unsigned long long key[1024];
  int n = (int)ctrA[sid]; if (n > 1024) n = 1024;
  for (int i = threadIdx.x; i < 1024; i += 256)
    key[i] = (i < n) ? listA[(size_t)sid*1024 + i] : 0ull;
  __syncthreads();
  for (int len = 2; len <= 1024; len <<= 1) {
    for (int j = len >> 1; j > 0; j >>= 1) {
      for (int t = threadIdx.x; t < 512; t += 256) {
        int i = ((t & ~(j - 1)) << 1) | (t & (j - 1));
        int pp = i | j;
        unsigned long long a = key[i], bq = key[pp];
        bool desc = ((i & len) == 0);
        if ((a < bq) == desc) { key[i] = bq; key[pp] = a; }
      }
      __syncthreads();
    }
  }
  for (int r = threadIdx.x; r < 1000; r += 256) {
    unsigned long long k = key[r];
    uint32_t bits = (uint32_t)(k >> 32);
    uint32_t idx = 0xFFFFFFFFu - (uint32_t)(k & 0xFFFFFFFFull);
    float val = __uint_as_float(bits);
    float sc = sqrtf(fmaxf(val, 1e-12f));
    int cls = (int)(idx % NCLS); int loc = (int)(idx / NCLS);
    int hh = loc / W; int ww = loc - hh*W;
    float cx = (float)(ww*LSTR[l] + (LSTR[l] >> 1));
    float cy = (float)(hh*LSTR[l] + (LSTR[l] >> 1));
    const float* rg = regb + (size_t)(2*LCUM[l] + b*HW + loc)*4;
    int slot = b*5000 + l*1000 + r;
    cbox[slot*4 + 0] = cx - rg[0];
    cbox[slot*4 + 1] = cy - rg[1];
    cbox[slot*4 + 2] = cx + rg[2];
    cbox[slot*4 + 3] = cy + rg[3];
    cscr[slot] = sc;
    ccls[slot] = (float)cls;
  }
}

// ---------------- NMS ----------------
__global__ __launch_bounds__(1024)
void k_nms(const float* __restrict__ cbox, const float* __restrict__ cscr,
           const float* __restrict__ ccls, float* __restrict__ out) {
  const int b = blockIdx.x;
  const int tid = threadIdx.x;
  __shared__ float s[5000];
  __shared__ float wv[16]; __shared__ int wi[16];
  __shared__ float bbx[5]; __shared__ int sBi; __shared__ float sBv;
  float x1[5], y1[5], x2[5], y2[5], ar[5];
#pragma unroll
  for (int r = 0; r < 5; r++) {
    int j = tid + r*1024;
    if (j < 5000) {
      const float4 bx = *reinterpret_cast<const float4*>(cbox + ((size_t)b*5000 + j)*4);
      float off = ccls[b*5000 + j]*10000.0f;
      x1[r] = bx.x + off; y1[r] = bx.y + off; x2[r] = bx.z + off; y2[r] = bx.w + off;
      ar[r] = (x2[r] - x1[r])*(y2[r] - y1[r]);
      s[j] = cscr[b*5000 + j];
    }
  }
  __syncthreads();
  for (int it = 0; it < 100; ++it) {
    float best = -1e30f; int bi = 0x7FFFFFFF;
#pragma unroll
    for (int r = 0; r < 5; r++) {
      int j = tid + r*1024;
      if (j < 5000) {
        float v = s[j];
        if (v > best || (v == best && j < bi)) { best = v; bi = j; }
      }
    }
    for (int o = 32; o > 0; o >>= 1) {
      float ov = __shfl_down(best, o, 64); int oi = __shfl_down(bi, o, 64);
      if (ov > best || (ov == best && oi < bi)) { best = ov; bi = oi; }
    }
    if ((tid & 63) == 0) { wv[tid >> 6] = best; wi[tid >> 6] = bi; }
    __syncthreads();
    if (tid < 64) {
      float v = (tid < 16) ? wv[tid] : -1e30f; int ix = (tid < 16) ? wi[tid] : 0x7FFFFFFF;
      for (int o = 8; o > 0; o >>= 1) {
        float ov = __shfl_down(v, o, 64); int oi = __shfl_down(ix, o, 64);
        if (ov > v || (ov == v && oi < ix)) { v = ov; ix = oi; }
      }
      if (tid == 0) { sBi = ix; sBv = v; }
    }
    __syncthreads();
    const int pick = sBi; const float pv = sBv;
    if (tid == (pick & 1023)) {
      const int r = pick >> 10;
      bbx[0] = x1[r]; bbx[1] = y1[r]; bbx[2] = x2[r]; bbx[3] = y2[r]; bbx[4] = ar[r];
      float* orow = out + ((size_t)b*100 + it)*6;
      if (pv > 0.f) {
        const float4 obx = *reinterpret_cast<const float4*>(cbox + ((size_t)b*5000 + pick)*4);
        orow[0] = obx.x; orow[1] = obx.y; orow[2] = obx.z; orow[3] = obx.w;
        orow[4] = pv; orow[5] = ccls[b*5000 + pick];
      } else {
        orow[0] = 0.f; orow[1] = 0.f; orow[2] = 0.f; orow[3] = 0.f; orow[4] = 0.f; orow[5] = 0.f;
      }
    }
    __syncthreads();
    const float bx1 = bbx[0], by1 = bbx[1], bx2 = bbx[2], by2 = bbx[3], ba = bbx[4];
#pragma unroll
    for (int r = 0; r < 5; r++) {
      int j = tid + r*1024;
      if (j < 5000) {
        float ix1 = fmaxf(bx1, x1[r]), iy1 = fmaxf(by1, y1[r]);
        float ix2 = fminf(bx2, x2[r]), iy2 = fminf(by2, y2[r]);
        float iw = fmaxf(ix2 - ix1, 0.f), ih = fmaxf(iy2 - iy1, 0.f);
        float inter = iw*ih;
        float iou = inter/((ba + ar[r] - inter) + 1e-9f);
        if (iou > 0.6f || j == pick) s[j] = -1.0f;
      }
    }
    __syncthreads();
  }
}

// ---------------- host launch ----------------
static inline size_t alignup(size_t x) { return (x + 255) & ~(size_t)255; }

extern "C" void kernel_launch(void* const* d_in, const int* in_sizes, int n_in,
                              void* d_out, int out_size, void* d_ws, size_t ws_size,
                              hipStream_t stream) {
  const float* p0 = (const float*)d_in[0];
  const float* p1 = (const float*)d_in[1];
  const float* p2 = (const float*)d_in[2];
  const float* p3 = (const float*)d_in[3];
  const float* p4 = (const float*)d_in[4];
  const float* cls_w   = (const float*)d_in[5];
  const float* cls_b   = (const float*)d_in[6];
  const float* box_w   = (const float*)d_in[7];
  const float* box_b   = (const float*)d_in[8];
  const float* logit_w = (const float*)d_in[9];
  const float* logit_b = (const float*)d_in[10];
  const float* pred_w  = (const float*)d_in[11];
  const float* pred_b  = (const float*)d_in[12];
  const float* ctr_w   = (const float*)d_in[13];
  const float* ctr_b   = (const float*)d_in[14];
  const float* scales  = (const float*)d_in[15];

  const size_t ACT_BYTES = (size_t)2*CINCH*TOTHW*4;   // 41,506,816
  char* base = (char*)d_ws;
  float* A  = (float*)base;
  float* Bu = (float*)(base + ACT_BYTES);
  char* sm = base + 2*ACT_BYTES;
  float* regb = (float*)sm;            sm += alignup((size_t)4*2*TOTHW*4);
  float* ctrp = (float*)sm;            sm += alignup((size_t)2*TOTHW*4);
  uint32_t* hist = (uint32_t*)sm;      sm += alignup((size_t)40960*4);
  int* meta = (int*)sm;                sm += alignup((size_t)40*4);
  uint32_t* ctrA = (uint32_t*)sm;      sm += 256;
  uint32_t* ctrB = (uint32_t*)sm;      sm += 256;
  unsigned long long* listA = (unsigned long long*)sm; sm += alignup((size_t)10*1024*8);
  float* cbox = (float*)sm;            sm += alignup((size_t)2*5000*4*4);
  float* cscr = (float*)sm;            sm += alignup((size_t)2*5000*4);
  float* ccls = (float*)sm;            sm += alignup((size_t)2*5000*4);
  float* scores = A;                                   // reuse: A free when logits runs
  unsigned long long* listB = (unsigned long long*)Bu; // reuse: B free after logits reads it

  const size_t WSTRIDE = (size_t)CINCH*KTOT;           // per-layer weight stride

  hipLaunchKernelGGL(k_init, dim3(160), dim3(256), 0, stream, hist, ctrA, ctrB);

  // ---- box tower ----
  hipLaunchKernelGGL(k_stage, dim3(2048), dim3(256), 0, stream, p0, p1, p2, p3, p4, A);
  hipLaunchKernelGGL(conv_k<0>, dim3(NPXB128, 2), dim3(256), 0, stream, A,  box_w + 0*WSTRIDE, box_b + 0,   Bu, (const float*)nullptr);
  hipLaunchKernelGGL(conv_k<0>, dim3(NPXB128, 2), dim3(256), 0, stream, Bu, box_w + 1*WSTRIDE, box_b + 256, A,  (const float*)nullptr);
  hipLaunchKernelGGL(conv_k<0>, dim3(NPXB128, 2), dim3(256), 0, stream, A,  box_w + 2*WSTRIDE, box_b + 512, Bu, (const float*)nullptr);
  hipLaunchKernelGGL(conv_k<0>, dim3(NPXB128, 2), dim3(256), 0, stream, Bu, box_w + 3*WSTRIDE, box_b + 768, A,  (const float*)nullptr);
  hipLaunchKernelGGL(k_head, dim3(NPXB64), dim3(256), 0, stream, A, ctr_w, ctr_b, pred_w, pred_b, scales, ctrp, regb);

  // ---- cls tower ----
  hipLaunchKernelGGL(k_stage, dim3(2048), dim3(256), 0, stream, p0, p1, p2, p3, p4, Bu);
  hipLaunchKernelGGL(conv_k<0>, dim3(NPXB128, 2), dim3(256), 0, stream, Bu, cls_w + 0*WSTRIDE, cls_b + 0,   A,  (const float*)nullptr);
  hipLaunchKernelGGL(conv_k<0>, dim3(NPXB128, 2), dim3(256), 0, stream, A,  cls_w + 1*WSTRIDE, cls_b + 256, Bu, (const float*)nullptr);
  hipLaunchKernelGGL(conv_k<0>, dim3(NPXB128, 2), dim3(256), 0, stream, Bu, cls_w + 2*WSTRIDE, cls_b + 512, A,  (const float*)nullptr);
  hipLaunchKernelGGL(conv_k<0>, dim3(NPXB128, 2), dim3(256), 0, stream, A,  cls_w + 3*WSTRIDE, cls_b + 768, Bu, (const float*)nullptr);
  hipLaunchKernelGGL(conv_k<1>, dim3(NPXB128, 1), dim3(256), 0, stream, Bu, logit_w, logit_b, scores, ctrp);

  // ---- top-k + decode + NMS ----
  hipLaunchKernelGGL(k_hist,    dim3(297, 10), dim3(256), 0, stream, scores, hist);
  hipLaunchKernelGGL(k_select,  dim3(10), dim3(256), 0, stream, hist, meta);
  hipLaunchKernelGGL(k_collect, dim3(297, 10), dim3(256), 0, stream, scores, meta, listA, listB, ctrA, ctrB);
  hipLaunchKernelGGL(k_refine,  dim3(10), dim3(1024), 0, stream, meta, listB, listA, ctrA);
  hipLaunchKernelGGL(k_sortdec, dim3(10), dim3(256), 0, stream, listA, ctrA, regb, cbox, cscr, ccls);
  hipLaunchKernelGGL(k_nms,     dim3(2), dim3(1024), 0, stream, cbox, cscr, ccls, (float*)d_out);
}